// Round 1
// baseline (56.086 us; speedup 1.0000x reference)
//
#include <hip/hip_runtime.h>
#include <hip/hip_bf16.h>

#define CIN_ 16
#define COUT_ 32
#define NBATCH_ 16
#define H_ 64
#define W_ 64
#define HP_ 66
#define WP_ 66
#define F_ 10                  // silu + 8 bases + 1 zero pad
#define KPT_ (CIN_ * F_)       // 160 K per tap
#define PIXSH_ 160             // ushorts per pixel in g
#define ROWSH_ (WP_ * PIXSH_)  // ushorts per g row
#define LPIX_ 336              // LDS bytes per pixel (320 + 16 pad -> conflict-free)
#define LROW_ (WP_ * LPIX_)    // 22176 LDS bytes per row

typedef __attribute__((ext_vector_type(8))) short short8;
typedef __attribute__((ext_vector_type(4))) float f32x4;

__device__ __forceinline__ unsigned short f2bf(float f) {
    unsigned u = __builtin_bit_cast(unsigned, f);
    u += 0x7FFFu + ((u >> 16) & 1u);
    return (unsigned short)(u >> 16);
}

// silu + cubic B-spline bases on uniform knots t_j = 0.4*j - 2.2 (j=0..11)
__device__ __forceinline__ void kan_feat(float xv, float* f) {
    float b0[11], b1[10], b2[9];
#pragma unroll
    for (int j = 0; j < 11; ++j) {
        float tj = 0.4f * j - 2.2f;
        b0[j] = (xv >= tj && xv < tj + 0.4f) ? 1.0f : 0.0f;
    }
#pragma unroll
    for (int j = 0; j < 10; ++j) {
        float tj = 0.4f * j - 2.2f;
        b1[j] = (xv - tj) * 2.5f * b0[j] + (tj + 0.8f - xv) * 2.5f * b0[j + 1];
    }
#pragma unroll
    for (int j = 0; j < 9; ++j) {
        float tj = 0.4f * j - 2.2f;
        b2[j] = (xv - tj) * 1.25f * b1[j] + (tj + 1.2f - xv) * 1.25f * b1[j + 1];
    }
    f[0] = xv / (1.0f + expf(-xv));
#pragma unroll
    for (int j = 0; j < 8; ++j) {
        float tj = 0.4f * j - 2.2f;
        f[1 + j] = (xv - tj) * (1.0f / 1.2f) * b2[j] +
                   (tj + 1.6f - xv) * (1.0f / 1.2f) * b2[j + 1];
    }
    f[9] = 0.0f;
}

// Stage 1: g[b][hp][wp][i*10+f] bf16, padded coords (x=0 outside)
__global__ void kan_featurize(const float* __restrict__ x, unsigned short* __restrict__ g) {
    __shared__ unsigned short sbuf[16 * PIXSH_];
    int tid = threadIdx.x;
    int b = blockIdx.x / HP_;
    int hp = blockIdx.x % HP_;
    int wp0 = blockIdx.y * 16;
    int i = tid >> 4;
    int pw = tid & 15;
    int wp = wp0 + pw;
    int hy = hp - 1, wx = wp - 1;
    float xv = 0.0f;
    if (hy >= 0 && hy < H_ && wx >= 0 && wx < W_)
        xv = x[(((size_t)b * CIN_ + i) * H_ + hy) * W_ + wx];
    float f[10];
    kan_feat(xv, f);
    unsigned short* dstl = &sbuf[pw * PIXSH_ + i * F_];
#pragma unroll
    for (int j = 0; j < F_; ++j) dstl[j] = f2bf(f[j]);
    __syncthreads();
    int npix = WP_ - wp0; if (npix > 16) npix = 16;
    unsigned int* dst = (unsigned int*)(g + ((size_t)(b * HP_ + hp) * WP_ + wp0) * PIXSH_);
    const unsigned int* src = (const unsigned int*)sbuf;
    for (int q = tid; q < npix * (PIXSH_ / 2); q += 256) dst[q] = src[q];
}

// Stage 1.5: pack weights into per-lane MFMA B-fragment order
// layout: [tap(9)][chunk(5)][ntile(2)][lane(64)][8 bf16]
__global__ void kan_packw(const float* __restrict__ bw, const float* __restrict__ sw,
                          const float* __restrict__ sc, unsigned short* __restrict__ wpk) {
    int e = blockIdx.x * 256 + threadIdx.x;
    if (e >= 9 * 5 * 2 * 64) return;
    int lane = e & 63;
    int rest = e >> 6;
    int nt = rest & 1; rest >>= 1;
    int c = rest % 5;
    int tap = rest / 5;
    int n = nt * 16 + (lane & 15);
    __attribute__((aligned(16))) unsigned short vals[8];
#pragma unroll
    for (int j = 0; j < 8; ++j) {
        int kl = c * 32 + ((lane >> 4) << 3) + j;
        int ci = kl / F_, f = kl % F_;
        int idx9 = (n * CIN_ + ci) * 9 + tap;
        float v = 0.0f;
        if (f == 0) v = bw[idx9];
        else if (f <= 8) v = sw[idx9 * 8 + (f - 1)] * sc[idx9];
        vals[j] = f2bf(v);
    }
    *(uint4*)(wpk + (size_t)e * 8) = *(const uint4*)vals;
}

// Stage 2: implicit-GEMM conv. Block = (b, output row h). 4 waves, each 16 pixels x 32 outs.
__global__ __launch_bounds__(256, 2) void kan_gemm(const unsigned short* __restrict__ g,
                                                   const unsigned short* __restrict__ wpk,
                                                   float* __restrict__ out) {
    __shared__ char lA[3 * LROW_];   // 66528 B, 3 g-rows, pixel stride 336
    __shared__ char lB[10240];       // one tap's weight slab
    int tid = threadIdx.x;
    int bb = blockIdx.x >> 6;
    int hh = blockIdx.x & 63;

    // stage 3 consecutive g rows (contiguous in global) into padded-stride LDS
    const uint4* gsrc = (const uint4*)(g + (size_t)(bb * HP_ + hh) * ROWSH_);
    for (int q = tid; q < 3 * WP_ * 20; q += 256) {
        uint4 v = gsrc[q];
        int r = q / (WP_ * 20), qq = q % (WP_ * 20);
        int p = qq / 20, s = qq % 20;
        *(uint4*)(lA + r * LROW_ + p * LPIX_ + s * 16) = v;
    }

    f32x4 acc0 = {0.f, 0.f, 0.f, 0.f}, acc1 = {0.f, 0.f, 0.f, 0.f};
    int lane = tid & 63, wv = tid >> 6;
    int koff = (lane >> 4) << 4;             // byte offset of this lane's 8 bf16 in a 64B chunk
    int prow = (wv << 4) + (lane & 15);      // output pixel (w) this lane's A row covers

    for (int tap = 0; tap < 9; ++tap) {
        __syncthreads();  // prev tap's MFMAs done (lB) / A-stage done (tap 0)
        const uint4* wsrc = (const uint4*)(wpk + (size_t)tap * 5120);
        for (int q = tid; q < 640; q += 256) ((uint4*)lB)[q] = wsrc[q];
        __syncthreads();  // lB ready
        const char* arow = lA + (tap / 3) * LROW_ + (prow + tap % 3) * LPIX_ + koff;
#pragma unroll
        for (int c = 0; c < 5; ++c) {
            short8 av = *(const short8*)(arow + c * 64);
            short8 w0 = *(const short8*)(lB + (c * 2 + 0) * 1024 + lane * 16);
            short8 w1 = *(const short8*)(lB + (c * 2 + 1) * 1024 + lane * 16);
            acc0 = __builtin_amdgcn_mfma_f32_16x16x32_bf16(av, w0, acc0, 0, 0, 0);
            acc1 = __builtin_amdgcn_mfma_f32_16x16x32_bf16(av, w1, acc1, 0, 0, 0);
        }
    }

    // C/D layout: n = lane&15, m(pixel) = (lane>>4)*4 + reg  [HW-verified mapping]
    int nloc = lane & 15;
    int mb = (wv << 4) + ((lane >> 4) << 2);
    float* ob = out + (size_t)bb * COUT_ * H_ * W_ + (size_t)hh * W_;
#pragma unroll
    for (int r = 0; r < 4; ++r) {
        ob[(size_t)nloc * (H_ * W_) + mb + r] = acc0[r];
        ob[(size_t)(16 + nloc) * (H_ * W_) + mb + r] = acc1[r];
    }
}

// Fallback (only if workspace is too small): direct fp32 compute, slow but correct.
__global__ void kan_direct(const float* __restrict__ x, const float* __restrict__ bw,
                           const float* __restrict__ sw, const float* __restrict__ sc,
                           float* __restrict__ out) {
    int idx = blockIdx.x * 256 + threadIdx.x;
    if (idx >= NBATCH_ * COUT_ * H_ * W_) return;
    int w = idx & 63, hh = (idx >> 6) & 63, o = (idx >> 12) & 31, b = idx >> 17;
    float acc = 0.0f;
    for (int i = 0; i < CIN_; ++i)
        for (int ki = 0; ki < 3; ++ki)
            for (int kj = 0; kj < 3; ++kj) {
                int hy = hh + ki - 1, wx = w + kj - 1;
                float xv = (hy >= 0 && hy < H_ && wx >= 0 && wx < W_)
                               ? x[(((size_t)b * CIN_ + i) * H_ + hy) * W_ + wx]
                               : 0.0f;
                float f[10];
                kan_feat(xv, f);
                int idx9 = (o * CIN_ + i) * 9 + ki * 3 + kj;
                float a = f[0] * bw[idx9];
                float s = sc[idx9];
#pragma unroll
                for (int cc = 0; cc < 8; ++cc) a += f[1 + cc] * sw[idx9 * 8 + cc] * s;
                acc += a;
            }
    out[idx] = acc;
}

extern "C" void kernel_launch(void* const* d_in, const int* in_sizes, int n_in,
                              void* d_out, int out_size, void* d_ws, size_t ws_size,
                              hipStream_t stream) {
    const float* x  = (const float*)d_in[0];
    const float* bw = (const float*)d_in[1];
    const float* sw = (const float*)d_in[2];
    const float* sc = (const float*)d_in[3];
    float* out = (float*)d_out;

    size_t gBytes = (size_t)NBATCH_ * HP_ * WP_ * KPT_ * 2;  // 22,302,720
    size_t need = gBytes + (size_t)9 * 5 * 2 * 64 * 8 * 2;   // + 92,160
    if (ws_size >= need) {
        unsigned short* g   = (unsigned short*)d_ws;
        unsigned short* wpk = (unsigned short*)((char*)d_ws + gBytes);
        kan_featurize<<<dim3(NBATCH_ * HP_, 5), 256, 0, stream>>>(x, g);
        kan_packw<<<dim3(23), 256, 0, stream>>>(bw, sw, sc, wpk);
        kan_gemm<<<dim3(NBATCH_ * H_), 256, 0, stream>>>(g, wpk, out);
    } else {
        kan_direct<<<dim3((NBATCH_ * COUT_ * H_ * W_ + 255) / 256), 256, 0, stream>>>(
            x, bw, sw, sc, out);
    }
}

// Round 2
// 36.296 us; speedup vs baseline: 1.5453x; 1.5453x over previous
//
#include <hip/hip_runtime.h>
#include <hip/hip_bf16.h>

#define CIN_ 16
#define COUT_ 32
#define NBATCH_ 16
#define H_ 64
#define W_ 64
#define WP_ 66
#define F_ 10                   // silu + 8 bases + 1 zero pad -> K=160 per tap
#define LPIX_ 336               // LDS bytes per pixel (320 data + 16 pad; 336%128=80 -> all 8 16B slots, 2-way free)
#define LROW_ (WP_ * LPIX_)     // 22176 B per staged input row
#define ROWS_ 6                 // input rows staged per block (4 output rows)

typedef __attribute__((ext_vector_type(8))) short short8;
typedef __attribute__((ext_vector_type(4))) float f32x4;

__device__ __forceinline__ unsigned short f2bf(float f) {
    unsigned u = __builtin_bit_cast(unsigned, f);
    u += 0x7FFFu + ((u >> 16) & 1u);
    return (unsigned short)(u >> 16);
}
__device__ __forceinline__ unsigned pack2(float lo, float hi) {
    return (unsigned)f2bf(lo) | ((unsigned)f2bf(hi) << 16);
}

// Closed-form uniform cubic B-spline: knots t_j = 0.4j - 2.2. At cell m only
// bases j=m-3..m are nonzero; algebraically identical to the Cox-de Boor
// recursion in the reference (partition of unity verified).
__device__ __forceinline__ void kan_feat10(float xv, float* f) {
    float ua = (xv + 2.2f) * 2.5f;
    float mf = floorf(ua);
    int m = (int)mf;
    float u = ua - mf;
    bool ok = (ua >= 0.0f) && (ua < 11.0f);
    float u2 = u * u, u3 = u2 * u;
    const float c6 = 1.0f / 6.0f;
    float Bm  = u3 * c6;
    float Bm1 = (-3.f * u3 + 3.f * u2 + 3.f * u + 1.f) * c6;
    float Bm2 = (3.f * u3 - 6.f * u2 + 4.f) * c6;
    float om = 1.f - u;
    float Bm3 = om * om * om * c6;
    if (!ok) { Bm = 0.f; Bm1 = 0.f; Bm2 = 0.f; Bm3 = 0.f; }
    f[0] = xv / (1.f + __expf(-xv));   // silu
#pragma unroll
    for (int j = 0; j < 8; ++j) {
        float v = 0.f;
        v = (m == j)     ? Bm  : v;
        v = (m == j + 1) ? Bm1 : v;
        v = (m == j + 2) ? Bm2 : v;
        v = (m == j + 3) ? Bm3 : v;
        f[1 + j] = v;
    }
    f[9] = 0.f;
}

// Pack weights into per-lane MFMA B-fragment order (unchanged from round 1):
// layout [tap(9)][chunk(5)][ntile(2)][lane(64)][8 bf16], k = ci*10 + f
__global__ void kan_packw(const float* __restrict__ bw, const float* __restrict__ sw,
                          const float* __restrict__ sc, unsigned short* __restrict__ wpk) {
    int e = blockIdx.x * 256 + threadIdx.x;
    if (e >= 9 * 5 * 2 * 64) return;
    int lane = e & 63;
    int rest = e >> 6;
    int nt = rest & 1; rest >>= 1;
    int c = rest % 5;
    int tap = rest / 5;
    int n = nt * 16 + (lane & 15);
    __attribute__((aligned(16))) unsigned short vals[8];
#pragma unroll
    for (int j = 0; j < 8; ++j) {
        int kl = c * 32 + ((lane >> 4) << 3) + j;
        int ci = kl / F_, f = kl % F_;
        int idx9 = (n * CIN_ + ci) * 9 + tap;
        float v = 0.0f;
        if (f == 0) v = bw[idx9];
        else if (f <= 8) v = sw[idx9 * 8 + (f - 1)] * sc[idx9];
        vals[j] = f2bf(v);
    }
    *(uint4*)(wpk + (size_t)e * 8) = *(const uint4*)vals;
}

// Fused featurize + implicit-GEMM conv. Block = (batch, 4 output rows).
// grid = 256 blocks = 1/CU. One barrier total; 9-tap loop barrier-free.
__global__ __launch_bounds__(256, 1) void kan_fused(const float* __restrict__ x,
                                                    const unsigned short* __restrict__ wpk,
                                                    float* __restrict__ out) {
    __shared__ __align__(16) char lA[ROWS_ * LROW_];   // 133,056 B
    int tid = threadIdx.x;
    int bb = blockIdx.x >> 4;
    int rg = blockIdx.x & 15;

    // ---- Phase 1: features straight into LDS ----
    // lane map: ci = tid>>4, l = tid&15 (px offset). Per wave: 4 ci x 16 px ->
    // coalesced 64B x reads; LDS b32 writes 2-way bank-free.
    {
        int ci = tid >> 4;
        int l = tid & 15;
        for (int it = 0; it < 30; ++it) {
            int r = it / 5, pb = it - r * 5;
            int px = pb * 16 + l;
            if (px < WP_) {
                int hy = rg * 4 + r - 1;
                int wx = px - 1;
                float xv = 0.f;
                if (hy >= 0 && hy < H_ && wx >= 0 && wx < W_)
                    xv = x[(((size_t)bb * CIN_ + ci) * H_ + hy) * W_ + wx];
                float f[10];
                kan_feat10(xv, f);
                unsigned* dst = (unsigned*)(lA + r * LROW_ + px * LPIX_ + ci * 20);
#pragma unroll
                for (int q = 0; q < 5; ++q) dst[q] = pack2(f[2 * q], f[2 * q + 1]);
            }
        }
    }
    __syncthreads();

    // ---- Phase 2: GEMM. Wave wv owns output row 4*rg+wv (all 64 px x 32 out).
    int lane = tid & 63, wv = tid >> 6;
    int lrow = lane & 15, khalf = lane >> 4;

    f32x4 acc[4][2];
#pragma unroll
    for (int mt = 0; mt < 4; ++mt)
#pragma unroll
        for (int nt = 0; nt < 2; ++nt) acc[mt][nt] = (f32x4){0.f, 0.f, 0.f, 0.f};

    // B fragments double-buffered in registers, loaded from L2-resident wpk
    short8 B[2][5][2];
#pragma unroll
    for (int c = 0; c < 5; ++c)
#pragma unroll
        for (int nt = 0; nt < 2; ++nt)
            B[0][c][nt] = *(const short8*)(wpk + (size_t)(((0 * 5 + c) * 2 + nt) * 64 + lane) * 8);

#pragma unroll
    for (int tap = 0; tap < 9; ++tap) {
        int cur = tap & 1, nxt = cur ^ 1;
        if (tap < 8) {
#pragma unroll
            for (int c = 0; c < 5; ++c)
#pragma unroll
                for (int nt = 0; nt < 2; ++nt)
                    B[nxt][c][nt] = *(const short8*)(wpk +
                        (size_t)((((tap + 1) * 5 + c) * 2 + nt) * 64 + lane) * 8);
        }
        int ki = tap / 3, kj = tap - ki * 3;
        const char* abase = lA + (wv + ki) * LROW_ + (lrow + kj) * LPIX_ + khalf * 16;
#pragma unroll
        for (int c = 0; c < 5; ++c) {
            short8 a0 = *(const short8*)(abase + c * 64);
            short8 a1 = *(const short8*)(abase + 16 * LPIX_ + c * 64);
            short8 a2 = *(const short8*)(abase + 32 * LPIX_ + c * 64);
            short8 a3 = *(const short8*)(abase + 48 * LPIX_ + c * 64);
#pragma unroll
            for (int nt = 0; nt < 2; ++nt) {
                acc[0][nt] = __builtin_amdgcn_mfma_f32_16x16x32_bf16(a0, B[cur][c][nt], acc[0][nt], 0, 0, 0);
                acc[1][nt] = __builtin_amdgcn_mfma_f32_16x16x32_bf16(a1, B[cur][c][nt], acc[1][nt], 0, 0, 0);
                acc[2][nt] = __builtin_amdgcn_mfma_f32_16x16x32_bf16(a2, B[cur][c][nt], acc[2][nt], 0, 0, 0);
                acc[3][nt] = __builtin_amdgcn_mfma_f32_16x16x32_bf16(a3, B[cur][c][nt], acc[3][nt], 0, 0, 0);
            }
        }
    }

    // ---- Epilogue: C layout (16x16): channel = lane&15, px = khalf*4 + reg.
    // Lanes {g, g+16, g+32, g+48} write one full 64B line per channel.
    int hh = rg * 4 + wv;
    float* ob = out + (size_t)bb * COUT_ * (H_ * W_) + (size_t)hh * W_;
#pragma unroll
    for (int mt = 0; mt < 4; ++mt)
#pragma unroll
        for (int nt = 0; nt < 2; ++nt) {
            int och = nt * 16 + lrow;
            int pxb = mt * 16 + khalf * 4;
            *(f32x4*)(ob + (size_t)och * (H_ * W_) + pxb) = acc[mt][nt];
        }
}

// Fallback (only if workspace is too small): direct fp32 compute, slow but correct.
__global__ void kan_direct(const float* __restrict__ x, const float* __restrict__ bw,
                           const float* __restrict__ sw, const float* __restrict__ sc,
                           float* __restrict__ out) {
    int idx = blockIdx.x * 256 + threadIdx.x;
    if (idx >= NBATCH_ * COUT_ * H_ * W_) return;
    int w = idx & 63, hh = (idx >> 6) & 63, o = (idx >> 12) & 31, b = idx >> 17;
    float acc = 0.0f;
    for (int i = 0; i < CIN_; ++i)
        for (int ki = 0; ki < 3; ++ki)
            for (int kj = 0; kj < 3; ++kj) {
                int hy = hh + ki - 1, wx = w + kj - 1;
                float xv = (hy >= 0 && hy < H_ && wx >= 0 && wx < W_)
                               ? x[(((size_t)b * CIN_ + i) * H_ + hy) * W_ + wx]
                               : 0.0f;
                float f[10];
                kan_feat10(xv, f);
                int idx9 = (o * CIN_ + i) * 9 + ki * 3 + kj;
                float a = f[0] * bw[idx9];
                float s = sc[idx9];
#pragma unroll
                for (int cc = 0; cc < 8; ++cc) a += f[1 + cc] * sw[idx9 * 8 + cc] * s;
                acc += a;
            }
    out[idx] = acc;
}

extern "C" void kernel_launch(void* const* d_in, const int* in_sizes, int n_in,
                              void* d_out, int out_size, void* d_ws, size_t ws_size,
                              hipStream_t stream) {
    const float* x  = (const float*)d_in[0];
    const float* bw = (const float*)d_in[1];
    const float* sw = (const float*)d_in[2];
    const float* sc = (const float*)d_in[3];
    float* out = (float*)d_out;

    size_t need = (size_t)9 * 5 * 2 * 64 * 8 * 2;   // 92,160 B packed weights
    if (ws_size >= need) {
        unsigned short* wpk = (unsigned short*)d_ws;
        kan_packw<<<dim3(23), 256, 0, stream>>>(bw, sw, sc, wpk);
        kan_fused<<<dim3(NBATCH_ * 16), 256, 0, stream>>>(x, wpk, out);
    } else {
        kan_direct<<<dim3((NBATCH_ * COUT_ * H_ * W_ + 255) / 256), 256, 0, stream>>>(
            x, bw, sw, sc, out);
    }
}

// Round 3
// 27.177 us; speedup vs baseline: 2.0638x; 1.3356x over previous
//
#include <hip/hip_runtime.h>
#include <hip/hip_bf16.h>

#define CIN_ 16
#define COUT_ 32
#define NBATCH_ 16
#define H_ 64
#define W_ 64
#define F_ 10                   // silu + 8 bases + 1 zero pad -> K=160 per tap
#define LPIX_ 336               // LDS bytes per pixel (320 data + 16 pad; 21 slots of 16B, odd -> conflict-free)
#define PXT_ 34                 // staged pixels per row (32 out + 2 halo)
#define LROWT_ (PXT_ * LPIX_)   // 11424 B per staged input row
#define ROWS_ 6                 // staged input rows (4 output rows + 2 halo)
#define NSITE_ (ROWS_ * PXT_)   // 204 (row,px) sites per ci
#define NIT_ 13                 // ceil(204/16) prefetch iterations

typedef __attribute__((ext_vector_type(8))) short short8;
typedef __attribute__((ext_vector_type(4))) float f32x4;

__device__ __forceinline__ unsigned short f2bf(float f) {
    unsigned u = __builtin_bit_cast(unsigned, f);
    u += 0x7FFFu + ((u >> 16) & 1u);
    return (unsigned short)(u >> 16);
}
__device__ __forceinline__ unsigned pack2(float lo, float hi) {
    return (unsigned)f2bf(lo) | ((unsigned)f2bf(hi) << 16);
}

// Closed-form uniform cubic B-spline: knots t_j = 0.4j - 2.2. Algebraically
// identical to the reference's Cox-de Boor recursion (verified round 2).
__device__ __forceinline__ void kan_feat10(float xv, float* f) {
    float ua = (xv + 2.2f) * 2.5f;
    float mf = floorf(ua);
    int m = (int)mf;
    float u = ua - mf;
    bool ok = (ua >= 0.0f) && (ua < 11.0f);
    float u2 = u * u, u3 = u2 * u;
    const float c6 = 1.0f / 6.0f;
    float Bm  = u3 * c6;
    float Bm1 = (-3.f * u3 + 3.f * u2 + 3.f * u + 1.f) * c6;
    float Bm2 = (3.f * u3 - 6.f * u2 + 4.f) * c6;
    float om = 1.f - u;
    float Bm3 = om * om * om * c6;
    if (!ok) { Bm = 0.f; Bm1 = 0.f; Bm2 = 0.f; Bm3 = 0.f; }
    f[0] = xv / (1.f + __expf(-xv));   // silu
#pragma unroll
    for (int j = 0; j < 8; ++j) {
        float v = 0.f;
        v = (m == j)     ? Bm  : v;
        v = (m == j + 1) ? Bm1 : v;
        v = (m == j + 2) ? Bm2 : v;
        v = (m == j + 3) ? Bm3 : v;
        f[1 + j] = v;
    }
    f[9] = 0.f;
}

// Pack weights into per-lane MFMA B-fragment order:
// layout [tap(9)][chunk(5)][ntile(2)][lane(64)][8 bf16], k = ci*10 + f
__global__ void kan_packw(const float* __restrict__ bw, const float* __restrict__ sw,
                          const float* __restrict__ sc, unsigned short* __restrict__ wpk) {
    int e = blockIdx.x * 256 + threadIdx.x;
    if (e >= 9 * 5 * 2 * 64) return;
    int lane = e & 63;
    int rest = e >> 6;
    int nt = rest & 1; rest >>= 1;
    int c = rest % 5;
    int tap = rest / 5;
    int n = nt * 16 + (lane & 15);
    __attribute__((aligned(16))) unsigned short vals[8];
#pragma unroll
    for (int j = 0; j < 8; ++j) {
        int kl = c * 32 + ((lane >> 4) << 3) + j;
        int ci = kl / F_, f = kl % F_;
        int idx9 = (n * CIN_ + ci) * 9 + tap;
        float v = 0.0f;
        if (f == 0) v = bw[idx9];
        else if (f <= 8) v = sw[idx9 * 8 + (f - 1)] * sc[idx9];
        vals[j] = f2bf(v);
    }
    *(uint4*)(wpk + (size_t)e * 8) = *(const uint4*)vals;
}

// Fused featurize + implicit-GEMM conv. Block = (batch, 4 output rows, 32-px half).
// grid = 512 = 2 blocks/CU, 2 waves/SIMD. One barrier; tap loop barrier-free.
__global__ __launch_bounds__(256, 2) void kan_fused(const float* __restrict__ x,
                                                    const unsigned short* __restrict__ wpk,
                                                    float* __restrict__ out) {
    __shared__ __align__(16) char lA[ROWS_ * LROWT_];   // 68,544 B
    int tid = threadIdx.x;
    int bb = blockIdx.x >> 5;
    int rem = blockIdx.x & 31;
    int rg = rem >> 1;
    int wseg = rem & 1;
    int h0 = rg * 4;
    int w0 = wseg * 32;

    // ---- Phase 1: features into LDS, loads register-prefetched ----
    {
        int ci = tid >> 4;
        int l = tid & 15;
        const float* xb = x + ((size_t)bb * CIN_ + ci) * (H_ * W_);
        float xr[NIT_];
#pragma unroll
        for (int it = 0; it < NIT_; ++it) {
            int s = it * 16 + l;
            int r = s / PXT_;
            int lpx = s - r * PXT_;
            int hy = h0 + r - 1;
            int wx = w0 + lpx - 1;
            bool v = (s < NSITE_) && (hy >= 0) && (hy < H_) && (wx >= 0) && (wx < W_);
            xr[it] = v ? xb[hy * W_ + wx] : 0.f;   // all loads issue before any use
        }
#pragma unroll
        for (int it = 0; it < NIT_; ++it) {
            int s = it * 16 + l;
            if (s < NSITE_) {
                int r = s / PXT_;
                int lpx = s - r * PXT_;
                float f[10];
                kan_feat10(xr[it], f);
                unsigned* dst = (unsigned*)(lA + r * LROWT_ + lpx * LPIX_ + ci * 20);
#pragma unroll
                for (int q = 0; q < 5; ++q) dst[q] = pack2(f[2 * q], f[2 * q + 1]);
            }
        }
    }

    int lane = tid & 63, wv = tid >> 6;
    int lrow = lane & 15, khalf = lane >> 4;

    // B fragments double-buffered in registers; first tap prefetched before the
    // barrier so its L2 latency hides under the barrier wait.
    short8 B[2][5][2];
#pragma unroll
    for (int c = 0; c < 5; ++c)
#pragma unroll
        for (int nt = 0; nt < 2; ++nt)
            B[0][c][nt] = *(const short8*)(wpk + (size_t)((c * 2 + nt) * 64 + lane) * 8);

    __syncthreads();

    // ---- Phase 2: wave wv owns output row h0+wv, 32 px x 32 out (M2xN2) ----
    f32x4 acc[2][2];
#pragma unroll
    for (int mt = 0; mt < 2; ++mt)
#pragma unroll
        for (int nt = 0; nt < 2; ++nt) acc[mt][nt] = (f32x4){0.f, 0.f, 0.f, 0.f};

#pragma unroll
    for (int tap = 0; tap < 9; ++tap) {
        int cur = tap & 1, nxt = cur ^ 1;
        if (tap < 8) {
#pragma unroll
            for (int c = 0; c < 5; ++c)
#pragma unroll
                for (int nt = 0; nt < 2; ++nt)
                    B[nxt][c][nt] = *(const short8*)(wpk +
                        (size_t)((((tap + 1) * 5 + c) * 2 + nt) * 64 + lane) * 8);
        }
        int ki = tap / 3, kj = tap - ki * 3;
        const char* abase = lA + (wv + ki) * LROWT_ + (lrow + kj) * LPIX_ + khalf * 16;
#pragma unroll
        for (int c = 0; c < 5; ++c) {
            short8 a0 = *(const short8*)(abase + c * 64);
            short8 a1 = *(const short8*)(abase + 16 * LPIX_ + c * 64);
#pragma unroll
            for (int nt = 0; nt < 2; ++nt) {
                acc[0][nt] = __builtin_amdgcn_mfma_f32_16x16x32_bf16(a0, B[cur][c][nt], acc[0][nt], 0, 0, 0);
                acc[1][nt] = __builtin_amdgcn_mfma_f32_16x16x32_bf16(a1, B[cur][c][nt], acc[1][nt], 0, 0, 0);
            }
        }
    }

    // ---- Epilogue: C layout (16x16): channel = lane&15, px = khalf*4 + reg ----
    int hh = h0 + wv;
    float* ob = out + (size_t)bb * COUT_ * (H_ * W_) + (size_t)hh * W_ + w0;
#pragma unroll
    for (int mt = 0; mt < 2; ++mt)
#pragma unroll
        for (int nt = 0; nt < 2; ++nt) {
            int och = nt * 16 + lrow;
            int pxb = mt * 16 + khalf * 4;
            *(f32x4*)(ob + (size_t)och * (H_ * W_) + pxb) = acc[mt][nt];
        }
}

// Fallback (only if workspace is too small): direct fp32 compute, slow but correct.
__global__ void kan_direct(const float* __restrict__ x, const float* __restrict__ bw,
                           const float* __restrict__ sw, const float* __restrict__ sc,
                           float* __restrict__ out) {
    int idx = blockIdx.x * 256 + threadIdx.x;
    if (idx >= NBATCH_ * COUT_ * H_ * W_) return;
    int w = idx & 63, hh = (idx >> 6) & 63, o = (idx >> 12) & 31, b = idx >> 17;
    float acc = 0.0f;
    for (int i = 0; i < CIN_; ++i)
        for (int ki = 0; ki < 3; ++ki)
            for (int kj = 0; kj < 3; ++kj) {
                int hy = hh + ki - 1, wx = w + kj - 1;
                float xv = (hy >= 0 && hy < H_ && wx >= 0 && wx < W_)
                               ? x[(((size_t)b * CIN_ + i) * H_ + hy) * W_ + wx]
                               : 0.0f;
                float f[10];
                kan_feat10(xv, f);
                int idx9 = (o * CIN_ + i) * 9 + ki * 3 + kj;
                float a = f[0] * bw[idx9];
                float s = sc[idx9];
#pragma unroll
                for (int cc = 0; cc < 8; ++cc) a += f[1 + cc] * sw[idx9 * 8 + cc] * s;
                acc += a;
            }
    out[idx] = acc;
}

extern "C" void kernel_launch(void* const* d_in, const int* in_sizes, int n_in,
                              void* d_out, int out_size, void* d_ws, size_t ws_size,
                              hipStream_t stream) {
    const float* x  = (const float*)d_in[0];
    const float* bw = (const float*)d_in[1];
    const float* sw = (const float*)d_in[2];
    const float* sc = (const float*)d_in[3];
    float* out = (float*)d_out;

    size_t need = (size_t)9 * 5 * 2 * 64 * 8 * 2;   // 92,160 B packed weights
    if (ws_size >= need) {
        unsigned short* wpk = (unsigned short*)d_ws;
        kan_packw<<<dim3(23), 256, 0, stream>>>(bw, sw, sc, wpk);
        kan_fused<<<dim3(NBATCH_ * 32), 256, 0, stream>>>(x, wpk, out);
    } else {
        kan_direct<<<dim3((NBATCH_ * COUT_ * H_ * W_ + 255) / 256), 256, 0, stream>>>(
            x, bw, sw, sc, out);
    }
}

// Round 4
// 21.581 us; speedup vs baseline: 2.5988x; 1.2593x over previous
//
#include <hip/hip_runtime.h>
#include <hip/hip_bf16.h>

#define CIN_ 16
#define COUT_ 32
#define NBATCH_ 16
#define H_ 64
#define W_ 64
#define F_ 10                   // silu + 8 bases + 1 zero pad -> K=160 per tap
#define LPIX_ 336               // LDS bytes per pixel (320 data + 16 pad; 21 slots of 16B, odd -> conflict-free)
#define PXT_ 34                 // staged pixels per row (32 out + 2 halo)
#define LROWT_ (PXT_ * LPIX_)   // 11424 B per staged input row
#define ROWS_ 6                 // staged input rows (4 output rows + 2 halo)
#define NSITE_ (ROWS_ * PXT_)   // 204 (row,px) sites per ci
#define NIT_ 13                 // ceil(204/16) prefetch iterations

typedef __attribute__((ext_vector_type(8))) short short8;
typedef __attribute__((ext_vector_type(4))) float f32x4;

__device__ __forceinline__ unsigned short f2bf(float f) {
    unsigned u = __builtin_bit_cast(unsigned, f);
    u += 0x7FFFu + ((u >> 16) & 1u);
    return (unsigned short)(u >> 16);
}
__device__ __forceinline__ unsigned pack2(float lo, float hi) {
    return (unsigned)f2bf(lo) | ((unsigned)f2bf(hi) << 16);
}

// Pack weights into per-lane MFMA B-fragment order.
// NEW layout: [tap(9)][nt(2)][c(5)][lane(64)][8 bf16], k = ci*10 + f.
// Inverted scheme: thread owns (n,ci,tap); contiguous sw loads, scattered
// u16 stores (incl. f=9 zeros -> every wpk byte written, poison-safe).
__global__ void kan_packw(const float* __restrict__ bw, const float* __restrict__ sw,
                          const float* __restrict__ sc, unsigned short* __restrict__ wpk) {
    int e = blockIdx.x * 256 + threadIdx.x;   // e = (n*16+ci)*9+tap
    if (e >= 32 * 16 * 9) return;
    int n = e / 144;
    int ci = (e / 9) & 15;
    int tap = e % 9;
    float bwv = bw[e];
    float scv = sc[e];
    float4 s0 = *(const float4*)(sw + (size_t)e * 8);
    float4 s1 = *(const float4*)(sw + (size_t)e * 8 + 4);
    float swv[8] = {s0.x, s0.y, s0.z, s0.w, s1.x, s1.y, s1.z, s1.w};
    int nt = n >> 4, nl = n & 15;
#pragma unroll
    for (int f = 0; f < 10; ++f) {
        float v = (f == 0) ? bwv : (f <= 8 ? swv[f - 1] * scv : 0.0f);
        int k = ci * 10 + f;
        int c = k >> 5, r = k & 31;
        int lane = ((r >> 3) << 4) | nl;
        int j = r & 7;
        size_t off = ((size_t)(((tap * 2 + nt) * 5 + c) * 64 + lane)) * 8 + j;
        wpk[off] = f2bf(v);
    }
}

// Fused featurize + implicit-GEMM conv. Block = (batch, 4 output rows, 32-px half).
// grid = 512 = 2 blocks/CU, 2 waves/SIMD. One barrier; tap loop barrier-free.
// Wave wv -> (row-pair p = wv&1, out-channel half nt = wv>>1): M4xN1 tile,
// halves per-wave B-fragment VMEM traffic vs M2xN2.
__global__ __launch_bounds__(256, 2) void kan_fused(const float* __restrict__ x,
                                                    const unsigned short* __restrict__ wpk,
                                                    float* __restrict__ out) {
    __shared__ __align__(16) char lA[ROWS_ * LROWT_];   // 68,544 B
    int tid = threadIdx.x;
    int bb = blockIdx.x >> 5;
    int rem = blockIdx.x & 31;
    int rg = rem >> 1;
    int wseg = rem & 1;
    int h0 = rg * 4;
    int w0 = wseg * 32;

    // ---- Phase 1: features into LDS, loads register-prefetched ----
    {
        int ci = tid >> 4;
        int l = tid & 15;
        const float* xb = x + ((size_t)bb * CIN_ + ci) * (H_ * W_);
        float xr[NIT_];
#pragma unroll
        for (int it = 0; it < NIT_; ++it) {
            int s = it * 16 + l;
            int r = s / PXT_;
            int lpx = s - r * PXT_;
            int hy = h0 + r - 1;
            int wx = w0 + lpx - 1;
            bool v = (s < NSITE_) && (hy >= 0) && (hy < H_) && (wx >= 0) && (wx < W_);
            xr[it] = v ? xb[hy * W_ + wx] : 0.f;   // all loads in flight together
        }
#pragma unroll
        for (int it = 0; it < NIT_; ++it) {
            int s = it * 16 + l;
            if (s < NSITE_) {
                int r = s / PXT_;
                int lpx = s - r * PXT_;
                float xv = xr[it];
                // closed-form uniform cubic B-spline, knots t_j = 0.4j-2.2
                float ua = (xv + 2.2f) * 2.5f;
                float mf = floorf(ua);
                float u = ua - mf;
                bool ok = (ua >= 0.0f) && (ua < 11.0f);
                float u2 = u * u, u3 = u2 * u;
                const float c6 = 1.0f / 6.0f;
                float Bm  = u3 * c6;
                float Bm1 = (-3.f * u3 + 3.f * u2 + 3.f * u + 1.f) * c6;
                float Bm2 = (3.f * u3 - 6.f * u2 + 4.f) * c6;
                float om = 1.f - u;
                float Bm3 = om * om * om * c6;
                // window placement: shorts (m-2..m+1) = [Bm3,Bm2,Bm1,Bm];
                // overflow into pad short 9 is harmless (its weight is 0).
                unsigned P0 = pack2(Bm3, Bm2);
                unsigned P1 = pack2(Bm1, Bm);
                int sh = ok ? ((int)mf - 2) : 99;
                int a = sh >> 1;
                bool odd = sh & 1;
                unsigned Q0 = odd ? (P0 << 16) : P0;
                unsigned Q1 = odd ? ((P0 >> 16) | (P1 << 16)) : P1;
                unsigned Q2 = odd ? (P1 >> 16) : 0u;
                unsigned wq[5];
#pragma unroll
                for (int q = 0; q < 5; ++q)
                    wq[q] = (q == a) ? Q0 : (q == a + 1) ? Q1 : (q == a + 2) ? Q2 : 0u;
                float sil = xv / (1.f + __expf(-xv));
                wq[0] = (wq[0] & 0xFFFF0000u) | (unsigned)f2bf(sil);
                unsigned* dst = (unsigned*)(lA + r * LROWT_ + lpx * LPIX_ + ci * 20);
#pragma unroll
                for (int q = 0; q < 5; ++q) dst[q] = wq[q];
            }
        }
    }

    int lane = tid & 63, wv = tid >> 6;
    int lrow = lane & 15, khalf = lane >> 4;
    int p = wv & 1;    // row pair within the 4-row group
    int nt = wv >> 1;  // out-channel half

    // B fragments double-buffered in registers; tap-0 slab prefetched before
    // the barrier so its L2 latency hides under the barrier wait.
    short8 B[2][5];
#pragma unroll
    for (int c = 0; c < 5; ++c)
        B[0][c] = *(const short8*)(wpk + (size_t)((nt * 5 + c) * 64 + lane) * 8);

    __syncthreads();

    // ---- Phase 2: wave owns rows (h0+2p, h0+2p+1) x 32 px x 16 out ----
    f32x4 acc[4];
#pragma unroll
    for (int mi = 0; mi < 4; ++mi) acc[mi] = (f32x4){0.f, 0.f, 0.f, 0.f};

#pragma unroll
    for (int tap = 0; tap < 9; ++tap) {
        int cur = tap & 1, nxt = cur ^ 1;
        if (tap < 8) {
#pragma unroll
            for (int c = 0; c < 5; ++c)
                B[nxt][c] = *(const short8*)(wpk +
                    (size_t)((((tap + 1) * 2 + nt) * 5 + c) * 64 + lane) * 8);
        }
        int ki = tap / 3, kj = tap - ki * 3;
        const char* abase = lA + (2 * p + ki) * LROWT_ + (lrow + kj) * LPIX_ + khalf * 16;
        __builtin_amdgcn_s_setprio(1);
#pragma unroll
        for (int c = 0; c < 5; ++c) {
            short8 a0 = *(const short8*)(abase + c * 64);
            short8 a1 = *(const short8*)(abase + 16 * LPIX_ + c * 64);
            short8 a2 = *(const short8*)(abase + LROWT_ + c * 64);
            short8 a3 = *(const short8*)(abase + LROWT_ + 16 * LPIX_ + c * 64);
            acc[0] = __builtin_amdgcn_mfma_f32_16x16x32_bf16(a0, B[cur][c], acc[0], 0, 0, 0);
            acc[1] = __builtin_amdgcn_mfma_f32_16x16x32_bf16(a1, B[cur][c], acc[1], 0, 0, 0);
            acc[2] = __builtin_amdgcn_mfma_f32_16x16x32_bf16(a2, B[cur][c], acc[2], 0, 0, 0);
            acc[3] = __builtin_amdgcn_mfma_f32_16x16x32_bf16(a3, B[cur][c], acc[3], 0, 0, 0);
        }
        __builtin_amdgcn_s_setprio(0);
    }

    // ---- Epilogue: C layout (16x16): channel = lane&15, px = khalf*4 + reg ----
    int ch = nt * 16 + lrow;
    float* ob = out + (size_t)bb * COUT_ * (H_ * W_) + (size_t)ch * (H_ * W_);
#pragma unroll
    for (int mi = 0; mi < 4; ++mi) {
        int hh = h0 + 2 * p + (mi >> 1);
        int px = w0 + (mi & 1) * 16 + khalf * 4;
        __builtin_nontemporal_store(acc[mi], (f32x4*)(ob + (size_t)hh * W_ + px));
    }
}

// Fallback (only if workspace is too small): direct fp32 compute, slow but correct.
__device__ __forceinline__ void kan_feat10_ref(float xv, float* f) {
    float ua = (xv + 2.2f) * 2.5f;
    float mf = floorf(ua);
    int m = (int)mf;
    float u = ua - mf;
    bool ok = (ua >= 0.0f) && (ua < 11.0f);
    float u2 = u * u, u3 = u2 * u;
    const float c6 = 1.0f / 6.0f;
    float Bm  = u3 * c6;
    float Bm1 = (-3.f * u3 + 3.f * u2 + 3.f * u + 1.f) * c6;
    float Bm2 = (3.f * u3 - 6.f * u2 + 4.f) * c6;
    float om = 1.f - u;
    float Bm3 = om * om * om * c6;
    if (!ok) { Bm = 0.f; Bm1 = 0.f; Bm2 = 0.f; Bm3 = 0.f; }
    f[0] = xv / (1.f + __expf(-xv));
#pragma unroll
    for (int j = 0; j < 8; ++j) {
        float v = 0.f;
        v = (m == j)     ? Bm  : v;
        v = (m == j + 1) ? Bm1 : v;
        v = (m == j + 2) ? Bm2 : v;
        v = (m == j + 3) ? Bm3 : v;
        f[1 + j] = v;
    }
    f[9] = 0.f;
}

__global__ void kan_direct(const float* __restrict__ x, const float* __restrict__ bw,
                           const float* __restrict__ sw, const float* __restrict__ sc,
                           float* __restrict__ out) {
    int idx = blockIdx.x * 256 + threadIdx.x;
    if (idx >= NBATCH_ * COUT_ * H_ * W_) return;
    int w = idx & 63, hh = (idx >> 6) & 63, o = (idx >> 12) & 31, b = idx >> 17;
    float acc = 0.0f;
    for (int i = 0; i < CIN_; ++i)
        for (int ki = 0; ki < 3; ++ki)
            for (int kj = 0; kj < 3; ++kj) {
                int hy = hh + ki - 1, wx = w + kj - 1;
                float xv = (hy >= 0 && hy < H_ && wx >= 0 && wx < W_)
                               ? x[(((size_t)b * CIN_ + i) * H_ + hy) * W_ + wx]
                               : 0.0f;
                float f[10];
                kan_feat10_ref(xv, f);
                int idx9 = (o * CIN_ + i) * 9 + ki * 3 + kj;
                float a = f[0] * bw[idx9];
                float s = sc[idx9];
#pragma unroll
                for (int cc = 0; cc < 8; ++cc) a += f[1 + cc] * sw[idx9 * 8 + cc] * s;
                acc += a;
            }
    out[idx] = acc;
}

extern "C" void kernel_launch(void* const* d_in, const int* in_sizes, int n_in,
                              void* d_out, int out_size, void* d_ws, size_t ws_size,
                              hipStream_t stream) {
    const float* x  = (const float*)d_in[0];
    const float* bw = (const float*)d_in[1];
    const float* sw = (const float*)d_in[2];
    const float* sc = (const float*)d_in[3];
    float* out = (float*)d_out;

    size_t need = (size_t)9 * 2 * 5 * 64 * 8 * 2;   // 92,160 B packed weights
    if (ws_size >= need) {
        unsigned short* wpk = (unsigned short*)d_ws;
        kan_packw<<<dim3(18), 256, 0, stream>>>(bw, sw, sc, wpk);
        kan_fused<<<dim3(NBATCH_ * 32), 256, 0, stream>>>(x, wpk, out);
    } else {
        kan_direct<<<dim3((NBATCH_ * COUT_ * H_ * W_ + 255) / 256), 256, 0, stream>>>(
            x, bw, sw, sc, out);
    }
}